// Round 2
// baseline (912.382 us; speedup 1.0000x reference)
//
#include <hip/hip_runtime.h>
#include <math.h>

#define DIMC 1024
#define C2   2048
#define DR   256
#define DH   32
#define NE   4
#define NB   8
#define NN   2048
#define NM   16384   /* NB*NN */

/* ---- k_front tiling ---- */
#define TT 32
#define BK 128

/* =====================  K1: LN1 + GEMM(w_red) + LN2 → yf  ===================== */
__global__ __launch_bounds__(256) void k_front(
    const float* __restrict__ x, const float* __restrict__ t,
    const float* __restrict__ ln1g, const float* __restrict__ ln1b,
    const float* __restrict__ wred,
    const float* __restrict__ ln2g, const float* __restrict__ ln2b,
    float* __restrict__ yf)
{
    __shared__ float a_sh[TT * BK];        // 16 KB
    __shared__ float y_sh[TT * DR];        // 32 KB
    __shared__ float mean_sh[TT], rstd_sh[TT];

    const int tid = threadIdx.x;
    const int m0  = blockIdx.x * TT;

    /* ---- LN1 stats: 8 lanes per token ---- */
    {
        const int tok = tid >> 3, l8 = tid & 7;
        const float* xr = x + (size_t)(m0 + tok) * DIMC;
        const float* tr = t + (size_t)(m0 + tok) * DIMC;
        float s = 0.f, ss = 0.f;
        for (int i = 0; i < DIMC / 8; ++i) {
            float v1 = xr[l8 + i * 8];
            float v2 = tr[l8 + i * 8];
            s += v1 + v2;
            ss += v1 * v1 + v2 * v2;
        }
        s += __shfl_down(s, 4, 8);  ss += __shfl_down(ss, 4, 8);
        s += __shfl_down(s, 2, 8);  ss += __shfl_down(ss, 2, 8);
        s += __shfl_down(s, 1, 8);  ss += __shfl_down(ss, 1, 8);
        if (l8 == 0) {
            float mean = s * (1.f / C2);
            float var  = ss * (1.f / C2) - mean * mean;
            mean_sh[tok] = mean;
            rstd_sh[tok] = rsqrtf(var + 1e-5f);
        }
    }

    /* ---- GEMM: block tile TT x DR, thread tile 4 tok x 8 col ---- */
    const int cg = tid & 31, c0 = cg * 8;
    const int rg = tid >> 5, r0 = rg * 4;
    float acc[4][8];
#pragma unroll
    for (int r = 0; r < 4; ++r)
#pragma unroll
        for (int j = 0; j < 8; ++j) acc[r][j] = 0.f;

    for (int kc = 0; kc < C2 / BK; ++kc) {
        __syncthreads();
        /* stage normalized A tile */
#pragma unroll
        for (int i = 0; i < (TT * BK) / 256; ++i) {
            int flat = tid + i * 256;
            int tk = flat >> 7;          // /BK
            int kk = flat & (BK - 1);
            int k  = kc * BK + kk;
            int mm = m0 + tk;
            float v = (k < DIMC) ? x[(size_t)mm * DIMC + k]
                                 : t[(size_t)mm * DIMC + (k - DIMC)];
            a_sh[flat] = (v - mean_sh[tk]) * rstd_sh[tk] * ln1g[k] + ln1b[k];
        }
        __syncthreads();

        const float* wr = wred + (size_t)(kc * BK) * DR + c0;
#pragma unroll 2
        for (int kk = 0; kk < BK; kk += 4) {
            float4 a4[4];
#pragma unroll
            for (int r = 0; r < 4; ++r)
                a4[r] = *(const float4*)&a_sh[(r0 + r) * BK + kk];
#pragma unroll
            for (int q = 0; q < 4; ++q) {
                float4 wA = *(const float4*)(wr + (size_t)(kk + q) * DR);
                float4 wB = *(const float4*)(wr + (size_t)(kk + q) * DR + 4);
#pragma unroll
                for (int r = 0; r < 4; ++r) {
                    float a = (q == 0) ? a4[r].x : (q == 1) ? a4[r].y : (q == 2) ? a4[r].z : a4[r].w;
                    acc[r][0] += a * wA.x; acc[r][1] += a * wA.y;
                    acc[r][2] += a * wA.z; acc[r][3] += a * wA.w;
                    acc[r][4] += a * wB.x; acc[r][5] += a * wB.y;
                    acc[r][6] += a * wB.z; acc[r][7] += a * wB.w;
                }
            }
        }
    }
    __syncthreads();

    /* write y tile to LDS for LN2 stats */
#pragma unroll
    for (int r = 0; r < 4; ++r)
#pragma unroll
        for (int j = 0; j < 8; ++j)
            y_sh[(r0 + r) * DR + c0 + j] = acc[r][j];
    __syncthreads();

    /* LN2 stats (re-use mean_sh/rstd_sh, safe after barrier) */
    {
        const int tok = tid >> 3, l8 = tid & 7;
        float s = 0.f, ss = 0.f;
#pragma unroll 4
        for (int i = 0; i < DR / 8; ++i) {
            float v = y_sh[tok * DR + l8 + i * 8];
            s += v; ss += v * v;
        }
        s += __shfl_down(s, 4, 8);  ss += __shfl_down(ss, 4, 8);
        s += __shfl_down(s, 2, 8);  ss += __shfl_down(ss, 2, 8);
        s += __shfl_down(s, 1, 8);  ss += __shfl_down(ss, 1, 8);
        if (l8 == 0) {
            float mean = s * (1.f / DR);
            float var  = ss * (1.f / DR) - mean * mean;
            mean_sh[tok] = mean;
            rstd_sh[tok] = rsqrtf(var + 1e-5f);
        }
    }
    __syncthreads();

    /* apply LN2 + write yf */
#pragma unroll
    for (int r = 0; r < 4; ++r) {
        const int mm = m0 + r0 + r;
        const float mu = mean_sh[r0 + r], rs = rstd_sh[r0 + r];
        float o[8];
#pragma unroll
        for (int j = 0; j < 8; ++j)
            o[j] = (acc[r][j] - mu) * rs * ln2g[c0 + j] + ln2b[c0 + j];
        float4 v0 = make_float4(o[0], o[1], o[2], o[3]);
        float4 v1 = make_float4(o[4], o[5], o[6], o[7]);
        *(float4*)(yf + (size_t)mm * DR + c0)     = v0;
        *(float4*)(yf + (size_t)mm * DR + c0 + 4) = v1;
    }
}

/* =====================  K2: MoE (gating + 2 experts) → px, pt, imp, load  ===================== */
__global__ __launch_bounds__(256) void k_moe(
    const float* __restrict__ yf, const int* __restrict__ taskp,
    const float* __restrict__ wgate,
    const float* __restrict__ w1, const float* __restrict__ b1,
    const float* __restrict__ w2, const float* __restrict__ b2,
    float* __restrict__ px, float* __restrict__ pt,
    double* __restrict__ imp, double* __restrict__ loadc)
{
    __shared__ float yf_sh[4][DR];
    __shared__ float hg_sh[4][2][DH];
    __shared__ float red_sh[8];

    const int tid = threadIdx.x, w = tid >> 6, l = tid & 63;
    if (tid < 8) red_sh[tid] = 0.f;
    const int task = *taskp;
    const int m = blockIdx.x * 4 + w;

    float4 v4 = *(const float4*)(yf + (size_t)m * DR + l * 4);
    *(float4*)&yf_sh[w][l * 4] = v4;
    __syncthreads();

    /* gating logits */
    const float* wg = wgate + task * (DR * NE);
    float lg0 = 0.f, lg1 = 0.f, lg2 = 0.f, lg3 = 0.f;
    {
        const float vv[4] = {v4.x, v4.y, v4.z, v4.w};
#pragma unroll
        for (int i = 0; i < 4; ++i) {
            float4 wrow = *(const float4*)(wg + (l * 4 + i) * 4);
            float a = vv[i];
            lg0 += a * wrow.x; lg1 += a * wrow.y;
            lg2 += a * wrow.z; lg3 += a * wrow.w;
        }
    }
#pragma unroll
    for (int off = 32; off; off >>= 1) {
        lg0 += __shfl_xor(lg0, off); lg1 += __shfl_xor(lg1, off);
        lg2 += __shfl_xor(lg2, off); lg3 += __shfl_xor(lg3, off);
    }
    float lg[4] = {lg0, lg1, lg2, lg3};

    /* top-2, jax tie-break (lowest index wins) */
    int i0 = 0; float v0 = lg[0];
#pragma unroll
    for (int e = 1; e < 4; ++e) if (lg[e] > v0) { v0 = lg[e]; i0 = e; }
    int i1 = -1; float v1 = -INFINITY;
#pragma unroll
    for (int e = 0; e < 4; ++e) if (e != i0 && lg[e] > v1) { v1 = lg[e]; i1 = e; }
    const float g1 = 1.f / (1.f + expf(v0 - v1));
    const float g0 = 1.f - g1;

    /* expert hidden: lanes 0-31 → expert i0, lanes 32-63 → expert i1 */
    const int half = l >> 5, j = l & 31;
    const int e    = half ? i1 : i0;
    const float ge = half ? g1 : g0;
    const float* w1e = w1 + e * (DR * DH) + j;
    float h = b1[e * DH + j];
#pragma unroll 4
    for (int c = 0; c < DR; c += 4) {
        float4 y4 = *(const float4*)&yf_sh[w][c];
        h += y4.x * w1e[(c + 0) * DH] + y4.y * w1e[(c + 1) * DH]
           + y4.z * w1e[(c + 2) * DH] + y4.w * w1e[(c + 3) * DH];
    }
    hg_sh[w][half][j] = ge * fmaxf(h, 0.f);
    __syncthreads();

    /* expert out, gate-weighted sum; lane holds 4 outputs o0..o0+3 */
    const int o0 = l * 4;
    float4 ym;
    {
        float4 ba = *(const float4*)(b2 + i0 * DR + o0);
        float4 bb = *(const float4*)(b2 + i1 * DR + o0);
        ym.x = g0 * ba.x + g1 * bb.x;
        ym.y = g0 * ba.y + g1 * bb.y;
        ym.z = g0 * ba.z + g1 * bb.z;
        ym.w = g0 * ba.w + g1 * bb.w;
    }
    const float* w2a = w2 + i0 * (DH * DR) + o0;
    const float* w2b = w2 + i1 * (DH * DR) + o0;
#pragma unroll 4
    for (int jj = 0; jj < DH; ++jj) {
        float ha = hg_sh[w][0][jj], hb = hg_sh[w][1][jj];
        float4 wa = *(const float4*)(w2a + jj * DR);
        float4 wb = *(const float4*)(w2b + jj * DR);
        ym.x += ha * wa.x + hb * wb.x;
        ym.y += ha * wa.y + hb * wb.y;
        ym.z += ha * wa.z + hb * wb.z;
        ym.w += ha * wa.w + hb * wb.w;
    }

    /* pooled sigmoid gates */
    float sm = ym.x + ym.y + ym.z + ym.w;
    float sx = (l < 32) ? sm : 0.f;
    float st = (l < 32) ? 0.f : sm;
#pragma unroll
    for (int off = 32; off; off >>= 1) { sx += __shfl_xor(sx, off); st += __shfl_xor(st, off); }
    if (l == 0) {
        px[m] = 1.f / (1.f + expf(-sx * (1.f / 128.f)));
        pt[m] = 1.f / (1.f + expf(-st * (1.f / 128.f)));
        atomicAdd(&red_sh[i0], g0);
        atomicAdd(&red_sh[i1], g1);
        atomicAdd(&red_sh[4 + i0], 1.f);
        atomicAdd(&red_sh[4 + i1], 1.f);
    }
    __syncthreads();
    if (tid < 4)        atomicAdd(&imp[tid], (double)red_sh[tid]);
    else if (tid < 8)   atomicAdd(&loadc[tid - 4], (double)red_sh[tid]);
}

/* =====================  K3: out_x/out_t + d1/d2 accumulation  ===================== */
#define K3CH 32
__global__ __launch_bounds__(256) void k_outxt(
    const float* __restrict__ x, const float* __restrict__ t,
    const float* __restrict__ past_x, const float* __restrict__ past_t,
    const float* __restrict__ px, const float* __restrict__ pt,
    const int* __restrict__ taskp, const float* __restrict__ mshift,
    float* __restrict__ out_x, float* __restrict__ out_t,
    float* __restrict__ d1, float* __restrict__ d2)
{
    const int b  = blockIdx.x >> 6;      /* NN/K3CH = 64 chunks per batch */
    const int ch = blockIdx.x & 63;
    const int c  = threadIdx.x * 4;
    const int task = *taskp;

    float4 shx = *(const float4*)(mshift + (size_t)(task * 2 + 0) * DIMC + c);
    float4 sht = *(const float4*)(mshift + (size_t)(task * 2 + 1) * DIMC + c);

    float a10 = 0.f, a11 = 0.f, a12 = 0.f, a13 = 0.f;
    float a20 = 0.f, a21 = 0.f, a22 = 0.f, a23 = 0.f;
    const int mbase = b * NN + ch * K3CH;

    for (int n = 0; n < K3CH; ++n) {
        const int m = mbase + n;
        const size_t off = (size_t)m * DIMC + c;
        const float pxv = px[m], ptv = pt[m];

        float4 xv = *(const float4*)(x + off);
        float4 p1 = *(const float4*)(past_x + off);
        float ox0 = pxv * xv.x + shx.x;
        float ox1 = pxv * xv.y + shx.y;
        float ox2 = pxv * xv.z + shx.z;
        float ox3 = pxv * xv.w + shx.w;
        out_x[off + 0] = ox0; out_x[off + 1] = ox1;
        out_x[off + 2] = ox2; out_x[off + 3] = ox3;
        a10 += fabsf(ox0 - p1.x); a11 += fabsf(ox1 - p1.y);
        a12 += fabsf(ox2 - p1.z); a13 += fabsf(ox3 - p1.w);

        float4 tv = *(const float4*)(t + off);
        float4 p2 = *(const float4*)(past_t + off);
        float ot0 = ptv * tv.x + sht.x;
        float ot1 = ptv * tv.y + sht.y;
        float ot2 = ptv * tv.z + sht.z;
        float ot3 = ptv * tv.w + sht.w;
        out_t[off + 0] = ot0; out_t[off + 1] = ot1;
        out_t[off + 2] = ot2; out_t[off + 3] = ot3;
        a20 += fabsf(ot0 - p2.x); a21 += fabsf(ot1 - p2.y);
        a22 += fabsf(ot2 - p2.z); a23 += fabsf(ot3 - p2.w);
    }
    atomicAdd(&d1[b * DIMC + c + 0], a10);
    atomicAdd(&d1[b * DIMC + c + 1], a11);
    atomicAdd(&d1[b * DIMC + c + 2], a12);
    atomicAdd(&d1[b * DIMC + c + 3], a13);
    atomicAdd(&d2[b * DIMC + c + 0], a20);
    atomicAdd(&d2[b * DIMC + c + 1], a21);
    atomicAdd(&d2[b * DIMC + c + 2], a22);
    atomicAdd(&d2[b * DIMC + c + 3], a23);
}

/* =====================  K5: score-net s = relu(d @ ws1) @ ws2  ===================== */
__global__ __launch_bounds__(256) void k_score(
    const float* __restrict__ d1, const float* __restrict__ d2,
    const float* __restrict__ ws1, const float* __restrict__ ws2,
    float* __restrict__ sv)
{
    const int b = blockIdx.x >> 1, branch = blockIdx.x & 1;
    const float* d = (branch ? d2 : d1) + b * DIMC;
    const int j = threadIdx.x;

    float acc0 = 0.f, acc1 = 0.f, acc2 = 0.f, acc3 = 0.f;
    for (int i = 0; i < DIMC; ++i) {
        float dv = d[i] * (1.f / NN);
        const float* wr = ws1 + (size_t)i * DIMC + j;
        acc0 += dv * wr[0];
        acc1 += dv * wr[256];
        acc2 += dv * wr[512];
        acc3 += dv * wr[768];
    }
    float s = fmaxf(acc0, 0.f) * ws2[j]
            + fmaxf(acc1, 0.f) * ws2[j + 256]
            + fmaxf(acc2, 0.f) * ws2[j + 512]
            + fmaxf(acc3, 0.f) * ws2[j + 768];

    __shared__ float red[4];
#pragma unroll
    for (int off = 32; off; off >>= 1) s += __shfl_xor(s, off);
    if ((threadIdx.x & 63) == 0) red[threadIdx.x >> 6] = s;
    __syncthreads();
    if (threadIdx.x == 0) sv[b * 2 + branch] = red[0] + red[1] + red[2] + red[3];
}

/* =====================  K6: aux_loss + softmax combine weights  ===================== */
__global__ void k_final_small(const double* __restrict__ imp, const double* __restrict__ loadc,
                              const float* __restrict__ sv, float* __restrict__ wcomb,
                              float* __restrict__ aux_out)
{
    const int tid = threadIdx.x;
    if (tid == 0) {
        double mi = 0, qi = 0, ml = 0, ql = 0;
        for (int e = 0; e < 4; ++e) {
            mi += imp[e]; qi += imp[e] * imp[e];
            ml += loadc[e]; ql += loadc[e] * loadc[e];
        }
        mi *= 0.25; qi *= 0.25; ml *= 0.25; ql *= 0.25;
        double vi = qi - mi * mi, vl = ql - ml * ml;
        *aux_out = (float)(vi / (mi * mi + 1e-10) + vl / (ml * ml + 1e-10));
    }
    if (tid < 8) {
        float s1 = sv[tid * 2 + 0], s2 = sv[tid * 2 + 1];
        float mx = fmaxf(s1, s2);
        float e1 = expf(s1 - mx), e2 = expf(s2 - mx);
        float inv = 1.f / (e1 + e2);
        wcomb[tid * 2 + 0] = e2 * inv;   /* w[:,1] → multiplies out_x */
        wcomb[tid * 2 + 1] = e1 * inv;   /* w[:,0] → multiplies out_t */
    }
}

/* =====================  K7: final combine  ===================== */
__global__ __launch_bounds__(256) void k_combine(
    const float* __restrict__ out_x, const float* __restrict__ out_t,
    const float* __restrict__ wcomb, float* __restrict__ out)
{
    const size_t i4 = ((size_t)blockIdx.x * 256 + threadIdx.x) * 4;
    const int b = (int)(i4 >> 21);   /* / (NN*DIMC) */
    const float wx = wcomb[b * 2 + 0], wt = wcomb[b * 2 + 1];
    float4 o;
    o.x = wx * out_x[i4 + 0] + wt * out_t[i4 + 0];
    o.y = wx * out_x[i4 + 1] + wt * out_t[i4 + 1];
    o.z = wx * out_x[i4 + 2] + wt * out_t[i4 + 2];
    o.w = wx * out_x[i4 + 3] + wt * out_t[i4 + 3];
    *(float4*)(out + i4) = o;
}

/* =====================  launch  ===================== */
extern "C" void kernel_launch(void* const* d_in, const int* in_sizes, int n_in,
                              void* d_out, int out_size, void* d_ws, size_t ws_size,
                              hipStream_t stream)
{
    const float* x      = (const float*)d_in[0];
    const float* t      = (const float*)d_in[1];
    const float* past_x = (const float*)d_in[2];
    const float* past_t = (const float*)d_in[3];
    const int*   task   = (const int*)d_in[4];
    const float* ln1g   = (const float*)d_in[5];
    const float* ln1b   = (const float*)d_in[6];
    const float* wred   = (const float*)d_in[7];
    const float* ln2g   = (const float*)d_in[8];
    const float* ln2b   = (const float*)d_in[9];
    const float* wgate  = (const float*)d_in[10];
    const float* w1     = (const float*)d_in[11];
    const float* b1     = (const float*)d_in[12];
    const float* w2     = (const float*)d_in[13];
    const float* b2     = (const float*)d_in[14];
    const float* mshift = (const float*)d_in[15];
    const float* ws1    = (const float*)d_in[16];
    const float* ws2    = (const float*)d_in[17];

    /* ---- small accumulator block in d_ws (65,728 bytes; ws_size is at
       least this — the previous round's 16.9 MB layout overflowed d_ws and
       corrupted adjacent harness buffers) ---- */
    float* f     = (float*)d_ws;
    float* d1    = f;                      /* 8192 */
    float* d2    = f + 8192;               /* 8192 */
    float* sv    = f + 16384;              /* 16   */
    float* wcomb = f + 16400;              /* 16   */
    double* imp   = (double*)(f + 16416);  /* 4 doubles (8-byte aligned) */
    double* loadc = (double*)(f + 16424);  /* 4 doubles */

    float* out   = (float*)d_out;
    float* aux   = out + (size_t)NM * DIMC;        /* index 16777216 */
    float* out_x = aux + 1;                        /* odd offset — scalar access only */
    float* out_t = out_x + (size_t)NM * DIMC;

    /* ---- big scratch lives in the `out` region of d_out (16.7M floats).
       out is only written by k_combine (last kernel); yf/px/pt are dead by
       then, so no race. ---- */
    float* yf    = out;                    /* NM*DR = 4,194,304 floats */
    float* px    = yf + (size_t)NM * DR;   /* NM */
    float* pt    = px + NM;                /* NM */

    hipMemsetAsync(d_ws, 0, 16432 * sizeof(float), stream);

    k_front<<<NM / TT, 256, 0, stream>>>(x, t, ln1g, ln1b, wred, ln2g, ln2b, yf);
    k_moe<<<NM / 4, 256, 0, stream>>>(yf, task, wgate, w1, b1, w2, b2, px, pt, imp, loadc);
    k_outxt<<<NB * (NN / K3CH), 256, 0, stream>>>(x, t, past_x, past_t, px, pt, task,
                                                  mshift, out_x, out_t, d1, d2);
    k_score<<<16, 256, 0, stream>>>(d1, d2, ws1, ws2, sv);
    k_final_small<<<1, 64, 0, stream>>>(imp, loadc, sv, wcomb, aux);
    k_combine<<<16384, 256, 0, stream>>>(out_x, out_t, wcomb, out);
}

// Round 3
// 710.329 us; speedup vs baseline: 1.2844x; 1.2844x over previous
//
#include <hip/hip_runtime.h>
#include <math.h>

#define DIMC 1024
#define C2   2048
#define DR   256
#define DH   32
#define NE   4
#define NB   8
#define NN   2048
#define NM   16384   /* NB*NN */

typedef short bf16x8 __attribute__((ext_vector_type(8)));
typedef float f32x4  __attribute__((ext_vector_type(4)));

__device__ __forceinline__ unsigned short f2bf(float f) {
    union { float f; unsigned int u; } v; v.f = f;
    unsigned int r = v.u + 0x7fffu + ((v.u >> 16) & 1u);   /* RNE */
    return (unsigned short)(r >> 16);
}

/* =====================  K0: prep  W''[c][k] = bf16(g_k * W[k][c]),
   u[c] = sum_k g_k W[k][c],  beta[c] = sum_k b_k W[k][c]  ===================== */
__global__ __launch_bounds__(256) void k_prep(
    const float* __restrict__ wred, const float* __restrict__ g1,
    const float* __restrict__ b1v, unsigned short* __restrict__ wpp,
    float* __restrict__ u, float* __restrict__ beta)
{
    __shared__ unsigned short tsh[64][72];
    __shared__ float ush[64], bsh[64];
    const int tid = threadIdx.x;
    const int k0 = (blockIdx.x >> 2) * 64;   /* 32 k-tiles */
    const int c0 = (blockIdx.x & 3) * 64;    /* 4 c-tiles  */
    if (tid < 64) { ush[tid] = 0.f; bsh[tid] = 0.f; }
    __syncthreads();

    const int r = tid >> 2, cs = (tid & 3) * 16;
    const float gk = g1[k0 + r], bk = b1v[k0 + r];
#pragma unroll
    for (int i = 0; i < 4; ++i) {
        float4 wv = *(const float4*)(wred + (size_t)(k0 + r) * DR + c0 + cs + i * 4);
        const int cb = cs + i * 4;
        atomicAdd(&ush[cb + 0], gk * wv.x); atomicAdd(&ush[cb + 1], gk * wv.y);
        atomicAdd(&ush[cb + 2], gk * wv.z); atomicAdd(&ush[cb + 3], gk * wv.w);
        atomicAdd(&bsh[cb + 0], bk * wv.x); atomicAdd(&bsh[cb + 1], bk * wv.y);
        atomicAdd(&bsh[cb + 2], bk * wv.z); atomicAdd(&bsh[cb + 3], bk * wv.w);
        tsh[cb + 0][r] = f2bf(gk * wv.x);
        tsh[cb + 1][r] = f2bf(gk * wv.y);
        tsh[cb + 2][r] = f2bf(gk * wv.z);
        tsh[cb + 3][r] = f2bf(gk * wv.w);
    }
    __syncthreads();

    const int cc = tid >> 2, seg = (tid & 3) * 16;
    uint4 v0 = *(const uint4*)&tsh[cc][seg];
    uint4 v1 = *(const uint4*)&tsh[cc][seg + 8];
    unsigned short* dst = wpp + (size_t)(c0 + cc) * C2 + k0 + seg;
    *(uint4*)(dst)     = v0;
    *(uint4*)(dst + 8) = v1;
    if (tid < 64) {
        atomicAdd(&u[c0 + tid],    ush[tid]);
        atomicAdd(&beta[c0 + tid], bsh[tid]);
    }
}

/* =====================  K1: MFMA front — y = r*(v@W'') - r*mu*u + beta, then LN2  ===================== */
#define FT  64
#define FBK 64
#define LDA 72
#define LDB 72

__global__ __launch_bounds__(256) void k_front(
    const float* __restrict__ x, const float* __restrict__ t,
    const unsigned short* __restrict__ wpp,
    const float* __restrict__ u, const float* __restrict__ beta,
    const float* __restrict__ ln2g, const float* __restrict__ ln2b,
    float* __restrict__ yf)
{
    __shared__ unsigned short A_sh[FT * LDA];   /* 9216 B  */
    __shared__ unsigned short B_sh[DR * LDB];   /* 36864 B */
    __shared__ float us_sh[DR], be_sh[DR], g2_sh[DR], b2_sh[DR];
    __shared__ float mean_sh[FT], rstd_sh[FT];
    __shared__ float pls[FT][2], plss[FT][2];

    const int tid  = threadIdx.x;
    const int m0   = blockIdx.x * FT;
    const int lane = tid & 63;
    const int w    = tid >> 6;
    const int wr   = w & 1, wc = w >> 1;
    const int cl   = lane & 15, kg = lane >> 4;

    if (tid < DR) {
        us_sh[tid] = u[tid];   be_sh[tid] = beta[tid];
        g2_sh[tid] = ln2g[tid]; b2_sh[tid] = ln2b[tid];
    }

    /* staging maps */
    const int atok = tid >> 2, aks = (tid & 3) * 16;
    const int brow = tid >> 3, boff = (tid & 7) * 8;

    float s1 = 0.f, ss1 = 0.f;
    float4 ax[4];
    uint4  bw[8];

    /* prefetch chunk 0 (from x, k-base 0) */
    {
        const float* arow = x + (size_t)(m0 + atok) * DIMC + aks;
#pragma unroll
        for (int i = 0; i < 4; ++i) ax[i] = *(const float4*)(arow + i * 4);
#pragma unroll
        for (int i = 0; i < 8; ++i)
            bw[i] = *(const uint4*)(wpp + (size_t)(i * 32 + brow) * C2 + boff);
    }

    f32x4 acc[2][8];
#pragma unroll
    for (int rt = 0; rt < 2; ++rt)
#pragma unroll
        for (int ct = 0; ct < 8; ++ct) acc[rt][ct] = (f32x4){0.f, 0.f, 0.f, 0.f};

    for (int kc = 0; kc < 32; ++kc) {
        __syncthreads();
        /* LN1 stats + bf16 convert + LDS write (from prefetched regs) */
#pragma unroll
        for (int i = 0; i < 4; ++i) {
            float4 v = ax[i];
            s1  += v.x + v.y + v.z + v.w;
            ss1 += v.x * v.x + v.y * v.y + v.z * v.z + v.w * v.w;
            short4 p;
            p.x = (short)f2bf(v.x); p.y = (short)f2bf(v.y);
            p.z = (short)f2bf(v.z); p.w = (short)f2bf(v.w);
            *(short4*)&A_sh[atok * LDA + aks + i * 4] = p;
        }
#pragma unroll
        for (int i = 0; i < 8; ++i)
            *(uint4*)&B_sh[(i * 32 + brow) * LDB + boff] = bw[i];
        __syncthreads();

        if (kc < 31) {
            const int kn = kc + 1;
            const float* src = (kn < 16) ? x : t;
            const int kb = (kn < 16) ? kn * FBK : (kn - 16) * FBK;
            const float* arow = src + (size_t)(m0 + atok) * DIMC + kb + aks;
#pragma unroll
            for (int i = 0; i < 4; ++i) ax[i] = *(const float4*)(arow + i * 4);
#pragma unroll
            for (int i = 0; i < 8; ++i)
                bw[i] = *(const uint4*)(wpp + (size_t)(i * 32 + brow) * C2 + kn * FBK + boff);
        }

#pragma unroll
        for (int kk = 0; kk < 2; ++kk) {
            bf16x8 af0 = *(const bf16x8*)&A_sh[(wr * 32 + 0  + cl) * LDA + kk * 32 + kg * 8];
            bf16x8 af1 = *(const bf16x8*)&A_sh[(wr * 32 + 16 + cl) * LDA + kk * 32 + kg * 8];
#pragma unroll
            for (int ct = 0; ct < 8; ++ct) {
                bf16x8 bf = *(const bf16x8*)&B_sh[(wc * 128 + ct * 16 + cl) * LDB + kk * 32 + kg * 8];
                acc[0][ct] = __builtin_amdgcn_mfma_f32_16x16x32_bf16(af0, bf, acc[0][ct], 0, 0, 0);
                acc[1][ct] = __builtin_amdgcn_mfma_f32_16x16x32_bf16(af1, bf, acc[1][ct], 0, 0, 0);
            }
        }
    }

    /* LN1 stats reduce: 4 threads per token (consecutive lanes) */
    {
        float s = s1, ss = ss1;
        s += __shfl_xor(s, 1); ss += __shfl_xor(ss, 1);
        s += __shfl_xor(s, 2); ss += __shfl_xor(ss, 2);
        if ((tid & 3) == 0) {
            float m  = s * (1.f / 2048.f);
            float va = ss * (1.f / 2048.f) - m * m;
            mean_sh[atok] = m;
            rstd_sh[atok] = rsqrtf(va + 1e-5f);
        }
    }
    __syncthreads();

    /* epilogue: LN1 correction, LN2 stats (cross-wave via LDS), write yf */
    float rsum[2][4], rssq[2][4];
#pragma unroll
    for (int rt = 0; rt < 2; ++rt)
#pragma unroll
        for (int reg = 0; reg < 4; ++reg) { rsum[rt][reg] = 0.f; rssq[rt][reg] = 0.f; }

#pragma unroll
    for (int rt = 0; rt < 2; ++rt) {
#pragma unroll
        for (int ct = 0; ct < 8; ++ct) {
            const int col = wc * 128 + ct * 16 + cl;
            const float uu = us_sh[col], bb = be_sh[col];
#pragma unroll
            for (int reg = 0; reg < 4; ++reg) {
                const int tok = wr * 32 + rt * 16 + kg * 4 + reg;
                const float mu = mean_sh[tok], rr = rstd_sh[tok];
                float y = rr * acc[rt][ct][reg] - rr * mu * uu + bb;
                acc[rt][ct][reg] = y;
                rsum[rt][reg] += y; rssq[rt][reg] += y * y;
            }
        }
    }
#pragma unroll
    for (int mask = 1; mask <= 8; mask <<= 1)
#pragma unroll
        for (int rt = 0; rt < 2; ++rt)
#pragma unroll
            for (int reg = 0; reg < 4; ++reg) {
                rsum[rt][reg] += __shfl_xor(rsum[rt][reg], mask);
                rssq[rt][reg] += __shfl_xor(rssq[rt][reg], mask);
            }
    if (cl == 0) {
#pragma unroll
        for (int rt = 0; rt < 2; ++rt)
#pragma unroll
            for (int reg = 0; reg < 4; ++reg) {
                const int tok = wr * 32 + rt * 16 + kg * 4 + reg;
                pls[tok][wc]  = rsum[rt][reg];
                plss[tok][wc] = rssq[rt][reg];
            }
    }
    __syncthreads();

#pragma unroll
    for (int rt = 0; rt < 2; ++rt) {
#pragma unroll
        for (int reg = 0; reg < 4; ++reg) {
            const int tok = wr * 32 + rt * 16 + kg * 4 + reg;
            const float m2 = (pls[tok][0] + pls[tok][1]) * (1.f / 256.f);
            const float v2 = (plss[tok][0] + plss[tok][1]) * (1.f / 256.f) - m2 * m2;
            const float r2 = rsqrtf(v2 + 1e-5f);
            float* yr = yf + (size_t)(m0 + tok) * DR;
#pragma unroll
            for (int ct = 0; ct < 8; ++ct) {
                const int col = wc * 128 + ct * 16 + cl;
                yr[col] = (acc[rt][ct][reg] - m2) * r2 * g2_sh[col] + b2_sh[col];
            }
        }
    }
}

/* =====================  K2: MoE (unchanged, verified) ===================== */
__global__ __launch_bounds__(256) void k_moe(
    const float* __restrict__ yf, const int* __restrict__ taskp,
    const float* __restrict__ wgate,
    const float* __restrict__ w1, const float* __restrict__ b1,
    const float* __restrict__ w2, const float* __restrict__ b2,
    float* __restrict__ px, float* __restrict__ pt,
    double* __restrict__ imp, double* __restrict__ loadc)
{
    __shared__ float yf_sh[4][DR];
    __shared__ float hg_sh[4][2][DH];
    __shared__ float red_sh[8];

    const int tid = threadIdx.x, w = tid >> 6, l = tid & 63;
    if (tid < 8) red_sh[tid] = 0.f;
    const int task = *taskp;
    const int m = blockIdx.x * 4 + w;

    float4 v4 = *(const float4*)(yf + (size_t)m * DR + l * 4);
    *(float4*)&yf_sh[w][l * 4] = v4;
    __syncthreads();

    const float* wg = wgate + task * (DR * NE);
    float lg0 = 0.f, lg1 = 0.f, lg2 = 0.f, lg3 = 0.f;
    {
        const float vv[4] = {v4.x, v4.y, v4.z, v4.w};
#pragma unroll
        for (int i = 0; i < 4; ++i) {
            float4 wrow = *(const float4*)(wg + (l * 4 + i) * 4);
            float a = vv[i];
            lg0 += a * wrow.x; lg1 += a * wrow.y;
            lg2 += a * wrow.z; lg3 += a * wrow.w;
        }
    }
#pragma unroll
    for (int off = 32; off; off >>= 1) {
        lg0 += __shfl_xor(lg0, off); lg1 += __shfl_xor(lg1, off);
        lg2 += __shfl_xor(lg2, off); lg3 += __shfl_xor(lg3, off);
    }
    float lg[4] = {lg0, lg1, lg2, lg3};

    int i0 = 0; float v0 = lg[0];
#pragma unroll
    for (int e = 1; e < 4; ++e) if (lg[e] > v0) { v0 = lg[e]; i0 = e; }
    int i1 = -1; float v1 = -INFINITY;
#pragma unroll
    for (int e = 0; e < 4; ++e) if (e != i0 && lg[e] > v1) { v1 = lg[e]; i1 = e; }
    const float g1 = 1.f / (1.f + expf(v0 - v1));
    const float g0 = 1.f - g1;

    const int half = l >> 5, j = l & 31;
    const int e    = half ? i1 : i0;
    const float ge = half ? g1 : g0;
    const float* w1e = w1 + e * (DR * DH) + j;
    float h = b1[e * DH + j];
#pragma unroll 4
    for (int c = 0; c < DR; c += 4) {
        float4 y4 = *(const float4*)&yf_sh[w][c];
        h += y4.x * w1e[(c + 0) * DH] + y4.y * w1e[(c + 1) * DH]
           + y4.z * w1e[(c + 2) * DH] + y4.w * w1e[(c + 3) * DH];
    }
    hg_sh[w][half][j] = ge * fmaxf(h, 0.f);
    __syncthreads();

    const int o0 = l * 4;
    float4 ym;
    {
        float4 ba = *(const float4*)(b2 + i0 * DR + o0);
        float4 bb = *(const float4*)(b2 + i1 * DR + o0);
        ym.x = g0 * ba.x + g1 * bb.x;
        ym.y = g0 * ba.y + g1 * bb.y;
        ym.z = g0 * ba.z + g1 * bb.z;
        ym.w = g0 * ba.w + g1 * bb.w;
    }
    const float* w2a = w2 + i0 * (DH * DR) + o0;
    const float* w2b = w2 + i1 * (DH * DR) + o0;
#pragma unroll 4
    for (int jj = 0; jj < DH; ++jj) {
        float ha = hg_sh[w][0][jj], hb = hg_sh[w][1][jj];
        float4 wa = *(const float4*)(w2a + jj * DR);
        float4 wb = *(const float4*)(w2b + jj * DR);
        ym.x += ha * wa.x + hb * wb.x;
        ym.y += ha * wa.y + hb * wb.y;
        ym.z += ha * wa.z + hb * wb.z;
        ym.w += ha * wa.w + hb * wb.w;
    }

    float sm = ym.x + ym.y + ym.z + ym.w;
    float sx = (l < 32) ? sm : 0.f;
    float st = (l < 32) ? 0.f : sm;
#pragma unroll
    for (int off = 32; off; off >>= 1) { sx += __shfl_xor(sx, off); st += __shfl_xor(st, off); }
    if (l == 0) {
        px[m] = 1.f / (1.f + expf(-sx * (1.f / 128.f)));
        pt[m] = 1.f / (1.f + expf(-st * (1.f / 128.f)));
        atomicAdd(&red_sh[i0], g0);
        atomicAdd(&red_sh[i1], g1);
        atomicAdd(&red_sh[4 + i0], 1.f);
        atomicAdd(&red_sh[4 + i1], 1.f);
    }
    __syncthreads();
    if (tid < 4)        atomicAdd(&imp[tid], (double)red_sh[tid]);
    else if (tid < 8)   atomicAdd(&loadc[tid - 4], (double)red_sh[tid]);
}

/* =====================  K3: out_x/out_t (shifted-vec stores) + d1/d2  ===================== */
#define K3T 32
__global__ __launch_bounds__(256) void k_outxt(
    const float* __restrict__ x, const float* __restrict__ t,
    const float* __restrict__ past_x, const float* __restrict__ past_t,
    const float* __restrict__ px, const float* __restrict__ pt,
    const int* __restrict__ taskp, const float* __restrict__ mshift,
    float* __restrict__ out_x, float* __restrict__ out_t,
    float* __restrict__ d1, float* __restrict__ d2)
{
    __shared__ float oxs[DIMC], ots[DIMC];
    const int b  = blockIdx.x >> 6;
    const int ch = blockIdx.x & 63;
    const int tid = threadIdx.x;
    const int c  = tid * 4;
    const int task = *taskp;

    float4 shx = *(const float4*)(mshift + (size_t)(task * 2 + 0) * DIMC + c);
    float4 sht = *(const float4*)(mshift + (size_t)(task * 2 + 1) * DIMC + c);

    float a10 = 0.f, a11 = 0.f, a12 = 0.f, a13 = 0.f;
    float a20 = 0.f, a21 = 0.f, a22 = 0.f, a23 = 0.f;
    const int mbase = b * NN + ch * K3T;

    for (int n = 0; n < K3T; ++n) {
        const int m = mbase + n;
        const size_t off = (size_t)m * DIMC + c;
        const float pxv = px[m], ptv = pt[m];

        float4 xv = *(const float4*)(x + off);
        float4 p1 = *(const float4*)(past_x + off);
        float4 ox;
        ox.x = pxv * xv.x + shx.x; ox.y = pxv * xv.y + shx.y;
        ox.z = pxv * xv.z + shx.z; ox.w = pxv * xv.w + shx.w;
        a10 += fabsf(ox.x - p1.x); a11 += fabsf(ox.y - p1.y);
        a12 += fabsf(ox.z - p1.z); a13 += fabsf(ox.w - p1.w);
        *(float4*)&oxs[c] = ox;

        float4 tv = *(const float4*)(t + off);
        float4 p2 = *(const float4*)(past_t + off);
        float4 ot;
        ot.x = ptv * tv.x + sht.x; ot.y = ptv * tv.y + sht.y;
        ot.z = ptv * tv.z + sht.z; ot.w = ptv * tv.w + sht.w;
        a20 += fabsf(ot.x - p2.x); a21 += fabsf(ot.y - p2.y);
        a22 += fabsf(ot.z - p2.z); a23 += fabsf(ot.w - p2.w);
        *(float4*)&ots[c] = ot;
        __syncthreads();

        const size_t rb = (size_t)m * DIMC;
        if (tid < 255) {
            const int cj = 3 + 4 * tid;   /* out_x base is odd: rb+cj is 16B-aligned */
            float4 vx = make_float4(oxs[cj], oxs[cj+1], oxs[cj+2], oxs[cj+3]);
            *(float4*)(out_x + rb + cj) = vx;
            float4 vt = make_float4(ots[cj], ots[cj+1], ots[cj+2], ots[cj+3]);
            *(float4*)(out_t + rb + cj) = vt;
        } else {
            out_x[rb + 0] = oxs[0]; out_x[rb + 1] = oxs[1];
            out_x[rb + 2] = oxs[2]; out_x[rb + 1023] = oxs[1023];
            out_t[rb + 0] = ots[0]; out_t[rb + 1] = ots[1];
            out_t[rb + 2] = ots[2]; out_t[rb + 1023] = ots[1023];
        }
        __syncthreads();
    }
    atomicAdd(&d1[b * DIMC + c + 0], a10);
    atomicAdd(&d1[b * DIMC + c + 1], a11);
    atomicAdd(&d1[b * DIMC + c + 2], a12);
    atomicAdd(&d1[b * DIMC + c + 3], a13);
    atomicAdd(&d2[b * DIMC + c + 0], a20);
    atomicAdd(&d2[b * DIMC + c + 1], a21);
    atomicAdd(&d2[b * DIMC + c + 2], a22);
    atomicAdd(&d2[b * DIMC + c + 3], a23);
}

/* =====================  K5: score-net, parallel over j-chunks  ===================== */
__global__ __launch_bounds__(256) void k_score(
    const float* __restrict__ d1, const float* __restrict__ d2,
    const float* __restrict__ ws1, const float* __restrict__ ws2,
    float* __restrict__ sv)
{
    __shared__ float red1[4][64], red2[4][64];
    const int tid = threadIdx.x;
    const int b = blockIdx.x >> 4, jc = blockIdx.x & 15;
    const int j = jc * 64 + (tid & 63), part = tid >> 6;
    const float* d1r = d1 + b * DIMC + part * 256;
    const float* d2r = d2 + b * DIMC + part * 256;
    const float* wp  = ws1 + (size_t)(part * 256) * DIMC + j;

    float acc1 = 0.f, acc2 = 0.f;
    for (int i = 0; i < 256; ++i) {
        float w = wp[(size_t)i * DIMC];
        acc1 += d1r[i] * w;
        acc2 += d2r[i] * w;
    }
    red1[part][tid & 63] = acc1;
    red2[part][tid & 63] = acc2;
    __syncthreads();
    if (tid < 64) {
        float h1 = red1[0][tid] + red1[1][tid] + red1[2][tid] + red1[3][tid];
        float h2 = red2[0][tid] + red2[1][tid] + red2[2][tid] + red2[3][tid];
        const int jj = jc * 64 + tid;
        float s1 = fmaxf(h1 * (1.f / NN), 0.f) * ws2[jj];
        float s2 = fmaxf(h2 * (1.f / NN), 0.f) * ws2[jj];
#pragma unroll
        for (int mask = 1; mask <= 32; mask <<= 1) {
            s1 += __shfl_xor(s1, mask); s2 += __shfl_xor(s2, mask);
        }
        if (tid == 0) {
            atomicAdd(&sv[b * 2 + 0], s1);
            atomicAdd(&sv[b * 2 + 1], s2);
        }
    }
}

/* =====================  K6: aux_loss + softmax combine weights  ===================== */
__global__ void k_final_small(const double* __restrict__ imp, const double* __restrict__ loadc,
                              const float* __restrict__ sv, float* __restrict__ wcomb,
                              float* __restrict__ aux_out)
{
    const int tid = threadIdx.x;
    if (tid == 0) {
        double mi = 0, qi = 0, ml = 0, ql = 0;
        for (int e = 0; e < 4; ++e) {
            mi += imp[e]; qi += imp[e] * imp[e];
            ml += loadc[e]; ql += loadc[e] * loadc[e];
        }
        mi *= 0.25; qi *= 0.25; ml *= 0.25; ql *= 0.25;
        double vi = qi - mi * mi, vl = ql - ml * ml;
        *aux_out = (float)(vi / (mi * mi + 1e-10) + vl / (ml * ml + 1e-10));
    }
    if (tid < 8) {
        float s1 = sv[tid * 2 + 0], s2 = sv[tid * 2 + 1];
        float mx = fmaxf(s1, s2);
        float e1 = expf(s1 - mx), e2 = expf(s2 - mx);
        float inv = 1.f / (e1 + e2);
        wcomb[tid * 2 + 0] = e2 * inv;   /* w[:,1] → multiplies out_x */
        wcomb[tid * 2 + 1] = e1 * inv;   /* w[:,0] → multiplies out_t */
    }
}

/* =====================  K7: final combine (shifted-vec reads)  ===================== */
__global__ __launch_bounds__(256) void k_combine(
    const float* __restrict__ out_x, const float* __restrict__ out_t,
    const float* __restrict__ wcomb, float* __restrict__ out)
{
    __shared__ float oxs[DIMC], ots[DIMC];
    const int m = blockIdx.x;
    const size_t rb = (size_t)m * DIMC;
    const int b = m >> 11;
    const float wx = wcomb[b * 2 + 0], wt = wcomb[b * 2 + 1];
    const int tid = threadIdx.x;

    if (tid < 255) {
        const int cj = 3 + 4 * tid;
        float4 vx = *(const float4*)(out_x + rb + cj);
        oxs[cj] = vx.x; oxs[cj + 1] = vx.y; oxs[cj + 2] = vx.z; oxs[cj + 3] = vx.w;
        float4 vt = *(const float4*)(out_t + rb + cj);
        ots[cj] = vt.x; ots[cj + 1] = vt.y; ots[cj + 2] = vt.z; ots[cj + 3] = vt.w;
    } else {
        oxs[0] = out_x[rb + 0]; oxs[1] = out_x[rb + 1];
        oxs[2] = out_x[rb + 2]; oxs[1023] = out_x[rb + 1023];
        ots[0] = out_t[rb + 0]; ots[1] = out_t[rb + 1];
        ots[2] = out_t[rb + 2]; ots[1023] = out_t[rb + 1023];
    }
    __syncthreads();

    const int c = tid * 4;
    float4 o;
    o.x = wx * oxs[c + 0] + wt * ots[c + 0];
    o.y = wx * oxs[c + 1] + wt * ots[c + 1];
    o.z = wx * oxs[c + 2] + wt * ots[c + 2];
    o.w = wx * oxs[c + 3] + wt * ots[c + 3];
    *(float4*)(out + rb + c) = o;
}

/* =====================  launch  ===================== */
extern "C" void kernel_launch(void* const* d_in, const int* in_sizes, int n_in,
                              void* d_out, int out_size, void* d_ws, size_t ws_size,
                              hipStream_t stream)
{
    const float* x      = (const float*)d_in[0];
    const float* t      = (const float*)d_in[1];
    const float* past_x = (const float*)d_in[2];
    const float* past_t = (const float*)d_in[3];
    const int*   task   = (const int*)d_in[4];
    const float* ln1g   = (const float*)d_in[5];
    const float* ln1b   = (const float*)d_in[6];
    const float* wred   = (const float*)d_in[7];
    const float* ln2g   = (const float*)d_in[8];
    const float* ln2b   = (const float*)d_in[9];
    const float* wgate  = (const float*)d_in[10];
    const float* w1     = (const float*)d_in[11];
    const float* b1     = (const float*)d_in[12];
    const float* w2     = (const float*)d_in[13];
    const float* b2     = (const float*)d_in[14];
    const float* mshift = (const float*)d_in[15];
    const float* ws1    = (const float*)d_in[16];
    const float* ws2    = (const float*)d_in[17];

    /* small accumulators in d_ws (65,728 B — known-safe) */
    float* f     = (float*)d_ws;
    float* d1    = f;
    float* d2    = f + 8192;
    float* sv    = f + 16384;
    float* wcomb = f + 16400;
    double* imp   = (double*)(f + 16416);
    double* loadc = (double*)(f + 16424);

    float* out   = (float*)d_out;
    float* aux   = out + (size_t)NM * DIMC;
    float* out_x = aux + 1;                       /* odd float offset */
    float* out_t = out_x + (size_t)NM * DIMC;

    /* big scratch inside `out` region (dead before k_combine writes it):
       yf [0, 4194304) · W'' bf16 at float 8,000,000 (262,144 floats) ·
       u/beta at 8,400,000 (512 floats) · px/pt parked at region tail */
    float* yf  = out;
    unsigned short* wpp = (unsigned short*)(out + 8000000);
    float* u    = out + 8400000;
    float* beta = out + 8400256;
    float* px   = out + (size_t)NM * DIMC - 2 * NM;   /* 16,744,448 */
    float* pt   = px + NM;

    hipMemsetAsync(d_ws, 0, 16432 * sizeof(float), stream);
    hipMemsetAsync(u, 0, 512 * sizeof(float), stream);

    k_prep<<<128, 256, 0, stream>>>(wred, ln1g, ln1b, wpp, u, beta);
    k_front<<<NM / FT, 256, 0, stream>>>(x, t, wpp, u, beta, ln2g, ln2b, yf);
    k_moe<<<NM / 4, 256, 0, stream>>>(yf, task, wgate, w1, b1, w2, b2, px, pt, imp, loadc);
    k_outxt<<<NB * (NN / K3T), 256, 0, stream>>>(x, t, past_x, past_t, px, pt, task,
                                                 mshift, out_x, out_t, d1, d2);
    k_score<<<128, 256, 0, stream>>>(d1, d2, ws1, ws2, sv);
    k_final_small<<<1, 64, 0, stream>>>(imp, loadc, sv, wcomb, aux);
    k_combine<<<NM, 256, 0, stream>>>(out_x, out_t, wcomb, out);
}